// Round 1
// baseline (74.886 us; speedup 1.0000x reference)
//
#include <hip/hip_runtime.h>

#define SCHUNK 64   // S rows per block
#define TPB    128  // threads per block (2 waves)

__device__ __forceinline__ float4 f4zero() { return make_float4(0.f, 0.f, 0.f, 0.f); }

__device__ __forceinline__ float4 fma4(float4 a, float4 b, float4 c) {
    return make_float4(fmaf(a.x, b.x, c.x),
                       fmaf(a.y, b.y, c.y),
                       fmaf(a.z, b.z, c.z),
                       fmaf(a.w, b.w, c.w));
}

// out[b,s,w] = bias[w] + sum_{k=0..3} xm[b, s-3+k, w] * wgt[k,w]
// xm = x * (segpos != 0); xm at s<0 is zero-padding.
// cache[b,k,w] = xm[b, S-3+k, w] for k=0..2
__global__ __launch_bounds__(TPB) void conv1d_fwd(
    const float* __restrict__ x,
    const int*   __restrict__ segpos,
    const float* __restrict__ wgt,
    const float* __restrict__ bias,
    float* __restrict__ out,
    float* __restrict__ cache,
    int B, int S, int W)
{
    const int col = (blockIdx.x * TPB + threadIdx.x) * 4;  // float index in W
    if (col >= W) return;
    const int b  = blockIdx.z;
    const int s0 = blockIdx.y * SCHUNK;

    // per-thread constants (w is tiny, L2-resident)
    const float4 w0 = *(const float4*)(wgt + 0 * (size_t)W + col);
    const float4 w1 = *(const float4*)(wgt + 1 * (size_t)W + col);
    const float4 w2 = *(const float4*)(wgt + 2 * (size_t)W + col);
    const float4 w3 = *(const float4*)(wgt + 3 * (size_t)W + col);
    const float4 bv = *(const float4*)(bias + col);

    const int*   sp   = segpos + (size_t)b * S;
    const float* xcol = x   + ((size_t)b * S) * W + col;
    float*       ocol = out + ((size_t)b * S) * W + col;

    // masked load of xm[s]; s uniform across block -> sp[s] is a scalar branch
    auto loadxm = [&](int s) -> float4 {
        if (s >= 0 && sp[s] != 0)
            return *(const float4*)(xcol + (size_t)s * W);
        return f4zero();
    };

    // rolling window a0..a3 = xm[s-3..s]; warm-up the 3 trailing rows
    float4 a0 = loadxm(s0 - 3);
    float4 a1 = loadxm(s0 - 2);
    float4 a2 = loadxm(s0 - 1);
    float4 a3;

    for (int i = 0; i < SCHUNK; i += 4) {
        const int s = s0 + i;
        // step 0: window = (a0,a1,a2,new a3)
        a3 = loadxm(s);
        float4 r = fma4(w3, a3, fma4(w2, a2, fma4(w1, a1, fma4(w0, a0, bv))));
        *(float4*)(ocol + (size_t)s * W) = r;
        // step 1: window = (a1,a2,a3,new a0)
        a0 = loadxm(s + 1);
        r = fma4(w3, a0, fma4(w2, a3, fma4(w1, a2, fma4(w0, a1, bv))));
        *(float4*)(ocol + (size_t)(s + 1) * W) = r;
        // step 2: window = (a2,a3,a0,new a1)
        a1 = loadxm(s + 2);
        r = fma4(w3, a1, fma4(w2, a0, fma4(w1, a3, fma4(w0, a2, bv))));
        *(float4*)(ocol + (size_t)(s + 2) * W) = r;
        // step 3: window = (a3,a0,a1,new a2)
        a2 = loadxm(s + 3);
        r = fma4(w3, a2, fma4(w2, a1, fma4(w1, a0, fma4(w0, a3, bv))));
        *(float4*)(ocol + (size_t)(s + 3) * W) = r;
    }

    // new_cache = xm[:, S-3:, :] — only the last S-chunk's blocks write it
    if (blockIdx.y == gridDim.y - 1) {
        #pragma unroll
        for (int k = 0; k < 3; ++k) {
            const int s = S - 3 + k;
            *(float4*)(cache + ((size_t)b * 3 + k) * W + col) = loadxm(s);
        }
    }
}

extern "C" void kernel_launch(void* const* d_in, const int* in_sizes, int n_in,
                              void* d_out, int out_size, void* d_ws, size_t ws_size,
                              hipStream_t stream) {
    const float* x      = (const float*)d_in[0];
    const int*   segpos = (const int*)d_in[1];
    const float* wgt    = (const float*)d_in[2];
    const float* bias   = (const float*)d_in[3];

    const int W  = in_sizes[3];        // 2560
    const int BS = in_sizes[1];        // B*S = 16384
    const int S  = 4096;
    const int B  = BS / S;             // 4

    float* out   = (float*)d_out;
    float* cache = out + (size_t)B * S * W;  // outputs concatenated flat

    dim3 grid((W / 4 + TPB - 1) / TPB, S / SCHUNK, B);
    conv1d_fwd<<<grid, dim3(TPB), 0, stream>>>(x, segpos, wgt, bias, out, cache, B, S, W);
}

// Round 2
// 65.771 us; speedup vs baseline: 1.1386x; 1.1386x over previous
//
#include <hip/hip_runtime.h>

#define SCHUNK 16   // S rows per block (small -> big grid -> full occupancy)
#define TPB    128  // threads per block (2 waves)

__device__ __forceinline__ float4 fma4(float4 a, float4 b, float4 c) {
    return make_float4(fmaf(a.x, b.x, c.x),
                       fmaf(a.y, b.y, c.y),
                       fmaf(a.z, b.z, c.z),
                       fmaf(a.w, b.w, c.w));
}

// out[b,s,w] = bias[w] + sum_{k=0..3} xm[b, s-3+k, w] * wgt[k,w]
// xm = x * (segpos != 0); xm at s<0 is zero-padding.
// cache[b,k,w] = xm[b, S-3+k, w] for k=0..2
__global__ __launch_bounds__(TPB) void conv1d_fwd(
    const float* __restrict__ x,
    const int*   __restrict__ segpos,
    const float* __restrict__ wgt,
    const float* __restrict__ bias,
    float* __restrict__ out,
    float* __restrict__ cache,
    int B, int S, int W)
{
    const int col = (blockIdx.x * TPB + threadIdx.x) * 4;  // float index in W
    if (col >= W) return;
    const int b  = blockIdx.z;
    const int s0 = blockIdx.y * SCHUNK;

    const float4 w0 = *(const float4*)(wgt + 0 * (size_t)W + col);
    const float4 w1 = *(const float4*)(wgt + 1 * (size_t)W + col);
    const float4 w2 = *(const float4*)(wgt + 2 * (size_t)W + col);
    const float4 w3 = *(const float4*)(wgt + 3 * (size_t)W + col);
    const float4 bv = *(const float4*)(bias + col);

    const int*   sp   = segpos + (size_t)b * S;
    const float* xcol = x   + ((size_t)b * S) * W + col;
    float*       ocol = out + ((size_t)b * S) * W + col;

    // Branch-free masked row load: clamp address, multiply by 0/1 mask.
    // Straight-line code lets the compiler keep many loads in flight.
    auto ldrow = [&](int s) -> float4 {
        const int sc = s < 0 ? 0 : s;
        float4 v = *(const float4*)(xcol + (size_t)sc * W);
        const float m = (s >= 0 && sp[sc] != 0) ? 1.0f : 0.0f;
        v.x *= m; v.y *= m; v.z *= m; v.w *= m;
        return v;
    };

    // window p0..p2 = xm[s-3..s-1]; current batch c0..c3 = xm[s..s+3]
    float4 p0 = ldrow(s0 - 3);
    float4 p1 = ldrow(s0 - 2);
    float4 p2 = ldrow(s0 - 1);
    float4 c0 = ldrow(s0 + 0);
    float4 c1 = ldrow(s0 + 1);
    float4 c2 = ldrow(s0 + 2);
    float4 c3 = ldrow(s0 + 3);

    #pragma unroll
    for (int i = 0; i < SCHUNK; i += 4) {
        const int s = s0 + i;
        // prefetch next batch into fresh registers (no WAR on current window)
        float4 n0, n1, n2, n3;
        if (i + 4 < SCHUNK) {
            n0 = ldrow(s + 4);
            n1 = ldrow(s + 5);
            n2 = ldrow(s + 6);
            n3 = ldrow(s + 7);
        }
        float4 r;
        r = fma4(w3, c0, fma4(w2, p2, fma4(w1, p1, fma4(w0, p0, bv))));
        *(float4*)(ocol + (size_t)(s + 0) * W) = r;
        r = fma4(w3, c1, fma4(w2, c0, fma4(w1, p2, fma4(w0, p1, bv))));
        *(float4*)(ocol + (size_t)(s + 1) * W) = r;
        r = fma4(w3, c2, fma4(w2, c1, fma4(w1, c0, fma4(w0, p2, bv))));
        *(float4*)(ocol + (size_t)(s + 2) * W) = r;
        r = fma4(w3, c3, fma4(w2, c2, fma4(w1, c1, fma4(w0, c0, bv))));
        *(float4*)(ocol + (size_t)(s + 3) * W) = r;
        // rotate: window <- tail of current, current <- next
        p0 = c1; p1 = c2; p2 = c3;
        c0 = n0; c1 = n1; c2 = n2; c3 = n3;
    }

    // new_cache = xm[:, S-3:, :] — only last S-chunk blocks write it
    if (blockIdx.y == gridDim.y - 1) {
        #pragma unroll
        for (int k = 0; k < 3; ++k) {
            const int s = S - 3 + k;
            *(float4*)(cache + ((size_t)b * 3 + k) * W + col) = ldrow(s);
        }
    }
}

extern "C" void kernel_launch(void* const* d_in, const int* in_sizes, int n_in,
                              void* d_out, int out_size, void* d_ws, size_t ws_size,
                              hipStream_t stream) {
    const float* x      = (const float*)d_in[0];
    const int*   segpos = (const int*)d_in[1];
    const float* wgt    = (const float*)d_in[2];
    const float* bias   = (const float*)d_in[3];

    const int W  = in_sizes[3];        // 2560
    const int BS = in_sizes[1];        // B*S = 16384
    const int S  = 4096;
    const int B  = BS / S;             // 4

    float* out   = (float*)d_out;
    float* cache = out + (size_t)B * S * W;  // outputs concatenated flat

    dim3 grid((W / 4 + TPB - 1) / TPB, S / SCHUNK, B);
    conv1d_fwd<<<grid, dim3(TPB), 0, stream>>>(x, segpos, wgt, bias, out, cache, B, S, W);
}

// Round 4
// 57.640 us; speedup vs baseline: 1.2992x; 1.1411x over previous
//
#include <hip/hip_runtime.h>

#define SCHUNK 16   // S rows per block
#define TPB    128  // threads per block (2 waves)

typedef float vf4 __attribute__((ext_vector_type(4)));  // native vec for nontemporal builtins

__device__ __forceinline__ float4 fma4(float4 a, float4 b, float4 c) {
    return make_float4(fmaf(a.x, b.x, c.x),
                       fmaf(a.y, b.y, c.y),
                       fmaf(a.z, b.z, c.z),
                       fmaf(a.w, b.w, c.w));
}

__device__ __forceinline__ void store_nt(float* p, float4 v) {
    vf4 t; t.x = v.x; t.y = v.y; t.z = v.z; t.w = v.w;
    __builtin_nontemporal_store(t, (vf4*)p);
}

// out[b,s,w] = bias[w] + sum_{k=0..3} xm[b, s-3+k, w] * wgt[k,w]
// xm = x * (segpos != 0); xm at s<0 is zero-padding.
// cache[b,k,w] = xm[b, S-3+k, w] for k=0..2
__global__ __launch_bounds__(TPB) void conv1d_fwd(
    const float* __restrict__ x,
    const int*   __restrict__ segpos,
    const float* __restrict__ wgt,
    const float* __restrict__ bias,
    float* __restrict__ out,
    float* __restrict__ cache,
    int B, int S, int W)
{
    const int col = (blockIdx.x * TPB + threadIdx.x) * 4;  // float index in W
    if (col >= W) return;
    const int b  = blockIdx.z;
    const int s0 = blockIdx.y * SCHUNK;

    const float4 w0 = *(const float4*)(wgt + 0 * (size_t)W + col);
    const float4 w1 = *(const float4*)(wgt + 1 * (size_t)W + col);
    const float4 w2 = *(const float4*)(wgt + 2 * (size_t)W + col);
    const float4 w3 = *(const float4*)(wgt + 3 * (size_t)W + col);
    const float4 bv = *(const float4*)(bias + col);

    const int*   sp   = segpos + (size_t)b * S;
    const float* xcol = x   + ((size_t)b * S) * W + col;
    float*       ocol = out + ((size_t)b * S) * W + col;

    // Branch-free masked row load: clamp address, multiply by 0/1 mask.
    auto ldrow = [&](int s) -> float4 {
        const int sc = s < 0 ? 0 : s;
        float4 v = *(const float4*)(xcol + (size_t)sc * W);
        const float m = (s >= 0 && sp[sc] != 0) ? 1.0f : 0.0f;
        v.x *= m; v.y *= m; v.z *= m; v.w *= m;
        return v;
    };

    // Issue ALL row loads for this chunk as one straight-line batch:
    // 19 independent 16B loads per lane in flight (max memory-level parallelism).
    float4 rows[SCHUNK + 3];
    #pragma unroll
    for (int k = 0; k < SCHUNK + 3; ++k)
        rows[k] = ldrow(s0 - 3 + k);

    // Compute + streaming (nontemporal) stores: keep `out` from evicting x in L3.
    #pragma unroll
    for (int i = 0; i < SCHUNK; ++i) {
        float4 r = fma4(w3, rows[i + 3],
                   fma4(w2, rows[i + 2],
                   fma4(w1, rows[i + 1],
                   fma4(w0, rows[i + 0], bv))));
        store_nt(ocol + (size_t)(s0 + i) * W, r);
    }

    // new_cache = xm[:, S-3:, :] — only last S-chunk blocks write it
    if (blockIdx.y == gridDim.y - 1) {
        #pragma unroll
        for (int k = 0; k < 3; ++k) {
            store_nt(cache + ((size_t)b * 3 + k) * W + col, rows[SCHUNK + k]);
        }
    }
}

extern "C" void kernel_launch(void* const* d_in, const int* in_sizes, int n_in,
                              void* d_out, int out_size, void* d_ws, size_t ws_size,
                              hipStream_t stream) {
    const float* x      = (const float*)d_in[0];
    const int*   segpos = (const int*)d_in[1];
    const float* wgt    = (const float*)d_in[2];
    const float* bias   = (const float*)d_in[3];

    const int W  = in_sizes[3];        // 2560
    const int BS = in_sizes[1];        // B*S = 16384
    const int S  = 4096;
    const int B  = BS / S;             // 4

    float* out   = (float*)d_out;
    float* cache = out + (size_t)B * S * W;  // outputs concatenated flat

    dim3 grid((W / 4 + TPB - 1) / TPB, S / SCHUNK, B);
    conv1d_fwd<<<grid, dim3(TPB), 0, stream>>>(x, segpos, wgt, bias, out, cache, B, S, W);
}

// Round 5
// 52.367 us; speedup vs baseline: 1.4300x; 1.1007x over previous
//
#include <hip/hip_runtime.h>

#define SCHUNK 16   // S rows per block
#define TPB    128  // threads per block (2 waves)

typedef float vf4 __attribute__((ext_vector_type(4)));  // native vec for nontemporal builtins

__device__ __forceinline__ float4 fma4(float4 a, float4 b, float4 c) {
    return make_float4(fmaf(a.x, b.x, c.x),
                       fmaf(a.y, b.y, c.y),
                       fmaf(a.z, b.z, c.z),
                       fmaf(a.w, b.w, c.w));
}

__device__ __forceinline__ void store_nt(float* p, float4 v) {
    vf4 t; t.x = v.x; t.y = v.y; t.z = v.z; t.w = v.w;
    __builtin_nontemporal_store(t, (vf4*)p);
}

// out[b,s,w] = bias[w] + sum_{k=0..3} xm[b, s-3+k, w] * wgt[k,w]
// xm = x * (segpos != 0); xm at s<0 is zero-padding.
// cache[b,k,w] = xm[b, S-3+k, w] for k=0..2
//
// 1D grid + bijective XCD-chunked remap: XCD k gets contiguous work ids,
// so s-adjacent chunks (sharing 3 halo rows) run on the SAME XCD -> halo
// re-reads hit that XCD's L2 instead of HBM.
__global__ __launch_bounds__(TPB) void conv1d_fwd(
    const float* __restrict__ x,
    const int*   __restrict__ segpos,
    const float* __restrict__ wgt,
    const float* __restrict__ bias,
    float* __restrict__ out,
    float* __restrict__ cache,
    int B, int S, int W, int nCols, int nSy)
{
    // ---- bijective XCD swizzle (nwg % 8 == 0 by construction) ----
    const int nwg = gridDim.x;
    const int per = nwg >> 3;                       // ids per XCD
    const int nid = (blockIdx.x & 7) * per + (blockIdx.x >> 3);
    int t = nid;
    const int cb = t % nCols; t /= nCols;           // column block
    const int sy = t % nSy;   t /= nSy;             // s-chunk
    const int b  = t;                               // batch

    const int col = (cb * TPB + threadIdx.x) * 4;   // float index in W
    const int s0  = sy * SCHUNK;

    const float4 w0 = *(const float4*)(wgt + 0 * (size_t)W + col);
    const float4 w1 = *(const float4*)(wgt + 1 * (size_t)W + col);
    const float4 w2 = *(const float4*)(wgt + 2 * (size_t)W + col);
    const float4 w3 = *(const float4*)(wgt + 3 * (size_t)W + col);
    const float4 bv = *(const float4*)(bias + col);

    const int*   sp   = segpos + (size_t)b * S;
    const float* xcol = x   + ((size_t)b * S) * W + col;
    float*       ocol = out + ((size_t)b * S) * W + col;

    // Branch-free masked row load: clamp address, multiply by 0/1 mask.
    auto ldrow = [&](int s) -> float4 {
        const int sc = s < 0 ? 0 : s;
        float4 v = *(const float4*)(xcol + (size_t)sc * W);
        const float m = (s >= 0 && sp[sc] != 0) ? 1.0f : 0.0f;
        v.x *= m; v.y *= m; v.z *= m; v.w *= m;
        return v;
    };

    // Issue ALL row loads for this chunk as one straight-line batch:
    // 19 independent 16B loads per lane in flight (max memory-level parallelism).
    float4 rows[SCHUNK + 3];
    #pragma unroll
    for (int k = 0; k < SCHUNK + 3; ++k)
        rows[k] = ldrow(s0 - 3 + k);

    // Compute + streaming (nontemporal) stores: keep `out` from evicting x in L3.
    #pragma unroll
    for (int i = 0; i < SCHUNK; ++i) {
        float4 r = fma4(w3, rows[i + 3],
                   fma4(w2, rows[i + 2],
                   fma4(w1, rows[i + 1],
                   fma4(w0, rows[i + 0], bv))));
        store_nt(ocol + (size_t)(s0 + i) * W, r);
    }

    // new_cache = xm[:, S-3:, :] — only last S-chunk blocks write it
    if (sy == nSy - 1) {
        #pragma unroll
        for (int k = 0; k < 3; ++k) {
            store_nt(cache + ((size_t)b * 3 + k) * W + col, rows[SCHUNK + k]);
        }
    }
}

extern "C" void kernel_launch(void* const* d_in, const int* in_sizes, int n_in,
                              void* d_out, int out_size, void* d_ws, size_t ws_size,
                              hipStream_t stream) {
    const float* x      = (const float*)d_in[0];
    const int*   segpos = (const int*)d_in[1];
    const float* wgt    = (const float*)d_in[2];
    const float* bias   = (const float*)d_in[3];

    const int W  = in_sizes[3];        // 2560
    const int BS = in_sizes[1];        // B*S = 16384
    const int S  = 4096;
    const int B  = BS / S;             // 4

    float* out   = (float*)d_out;
    float* cache = out + (size_t)B * S * W;  // outputs concatenated flat

    const int nCols = (W / 4) / TPB;   // 5
    const int nSy   = S / SCHUNK;      // 256
    const int nwg   = nCols * nSy * B; // 5120 (divisible by 8)

    conv1d_fwd<<<dim3(nwg), dim3(TPB), 0, stream>>>(
        x, segpos, wgt, bias, out, cache, B, S, W, nCols, nSy);
}